// Round 3
// baseline (292.958 us; speedup 1.0000x reference)
//
#include <hip/hip_runtime.h>

// Attention_Layer: scores=d@e^T -> softmax -> value=attn@e -> tanh([value,d]@W+b)
// B=8 TE=4096 TD=1024 H=256 NH=256, f32 in/out.
// Round 3: barrier-free flash with 32x32x16 MFMA, all fragments loaded directly
// from global (L1/L2-hot), in-register softmax+P; fused combine+dense MFMA GEMM.

#define B_ 8
#define TE_ 4096
#define TD_ 1024
#define H_ 256
#define NS_ 8
#define CHUNK_ (TE_ / NS_)   // 512
#define NROW_ (B_ * TD_)     // 8192

typedef __attribute__((ext_vector_type(8))) short s16x8;
typedef __attribute__((ext_vector_type(16))) float fx16;
typedef __attribute__((ext_vector_type(4))) float fx4;
typedef __attribute__((ext_vector_type(4))) unsigned short u16x4;

#define MFMA32(a, b, c) __builtin_amdgcn_mfma_f32_32x32x16_bf16(a, b, c, 0, 0, 0)

__device__ __forceinline__ unsigned short f2bf(float x) {
  unsigned u = __float_as_uint(x);
  unsigned r = (u + 0x7fffu + ((u >> 16) & 1u)) >> 16;  // RNE
  return (unsigned short)r;
}
__device__ __forceinline__ float bf2f(unsigned short s) {
  return __uint_as_float(((unsigned)s) << 16);
}
// pack two already-bf16-representable f32 into one u32 (lo = f0, hi = f1)
__device__ __forceinline__ unsigned pk2(float f0, float f1) {
  return (__float_as_uint(f0) >> 16) | (__float_as_uint(f1) & 0xFFFF0000u);
}

// ---------------- prep_e: e(f32) -> ehi(RNE), elo(resid), eT(bf16,[B,H,TE])
__global__ __launch_bounds__(256) void prep_e(const float* __restrict__ e,
                                              unsigned short* __restrict__ ehi,
                                              unsigned short* __restrict__ elo,
                                              unsigned short* __restrict__ eT) {
  const int bid = blockIdx.x;          // 2048 = 8 * 64 * 4
  const int b = bid >> 8;
  const int s0 = ((bid >> 2) & 63) * 64;
  const int h0 = (bid & 3) * 64;
  const int tid = threadIdx.x;
  __shared__ unsigned short lt[64][65];

#pragma unroll
  for (int i = 0; i < 4; ++i) {
    const int row = (tid >> 4) + 16 * i;
    const int col = (tid & 15) * 4;
    const size_t go = (((size_t)b * TE_) + s0 + row) * H_ + h0 + col;
    const fx4 v = *(const fx4*)&e[go];
    u16x4 hv, lv;
#pragma unroll
    for (int j = 0; j < 4; ++j) {
      const unsigned short hb = f2bf(v[j]);
      hv[j] = hb;
      lv[j] = f2bf(v[j] - bf2f(hb));
      lt[row][col + j] = hb;
    }
    *(u16x4*)&ehi[go] = hv;
    *(u16x4*)&elo[go] = lv;
  }
  __syncthreads();
#pragma unroll
  for (int i = 0; i < 2; ++i) {
    const int idx = tid + 256 * i;     // 0..511
    const int hh = idx >> 3;
    const int sc = (idx & 7) * 8;
    s16x8 v;
#pragma unroll
    for (int j = 0; j < 8; ++j) v[j] = (short)lt[sc + j][hh];
    *(s16x8*)&eT[(((size_t)b * H_) + h0 + hh) * TE_ + s0 + sc] = v;
  }
}

// ---------------- prep_dw: d -> dh/dl bf16; W -> WT bf16 [256n][512k]
__global__ __launch_bounds__(256) void prep_dw(const float* __restrict__ dmat,
                                               const float* __restrict__ W,
                                               unsigned short* __restrict__ dh,
                                               unsigned short* __restrict__ dl,
                                               unsigned short* __restrict__ WT) {
  const int bid = blockIdx.x;
  __shared__ float wl[32][33];
  if (bid < 1024) {
    const size_t idx = ((size_t)bid * 256 + threadIdx.x) * 8;   // 2M elems total
    const fx4 a = *(const fx4*)&dmat[idx];
    const fx4 c = *(const fx4*)&dmat[idx + 4];
    u16x4 h0, l0, h1, l1;
#pragma unroll
    for (int j = 0; j < 4; ++j) {
      unsigned short hb = f2bf(a[j]);
      h0[j] = hb; l0[j] = f2bf(a[j] - bf2f(hb));
      hb = f2bf(c[j]);
      h1[j] = hb; l1[j] = f2bf(c[j] - bf2f(hb));
    }
    *(u16x4*)&dh[idx] = h0; *(u16x4*)&dh[idx + 4] = h1;
    *(u16x4*)&dl[idx] = l0; *(u16x4*)&dl[idx + 4] = l1;
  } else {
    const int tb = bid - 1024;         // 128 tiles: 16 k-tiles x 8 n-tiles
    const int k0 = (tb >> 3) * 32, n0 = (tb & 7) * 32;
    const int r = threadIdx.x >> 3, c4 = (threadIdx.x & 7) * 4;
    const fx4 v = *(const fx4*)&W[(size_t)(k0 + r) * 256 + n0 + c4];
#pragma unroll
    for (int j = 0; j < 4; ++j) wl[r][c4 + j] = v[j];
    __syncthreads();
    u16x4 o;
#pragma unroll
    for (int j = 0; j < 4; ++j) o[j] = f2bf(wl[c4 + j][r]);
    *(u16x4*)&WT[(size_t)(n0 + r) * 512 + k0 + c4] = o;
  }
}

// ---------------- flash3: barrier-free, 512 blocks x 4 waves, q32/wave
// QK^T swapped: S^T = e-tile(A) x d(B); 3-term hi/lo. PV: value^T = eT(A) x P(B).
__global__ __launch_bounds__(256, 2) void flash3(
    const unsigned short* __restrict__ ehi, const unsigned short* __restrict__ elo,
    const unsigned short* __restrict__ eT,
    const unsigned short* __restrict__ dh, const unsigned short* __restrict__ dl,
    unsigned short* __restrict__ pacc, float* __restrict__ pm,
    float* __restrict__ pl) {
  const int bid = blockIdx.x;          // 512 = 8ns x 8b x 8qb (ns->XCD)
  const int ns = bid & 7;
  const int rest = bid >> 3;
  const int b = rest >> 3;
  const int qb = rest & 7;
  const int tid = threadIdx.x;
  const int w = tid >> 6;
  const int lane = tid & 63;
  const int ln = lane & 31, hi = lane >> 5;
  const int q = qb * 128 + w * 32 + ln;
  const int R = b * TD_ + q;

  const size_t db = ((size_t)b * TD_ + q) * H_ + hi * 8;

  fx16 acc[8];
#pragma unroll
  for (int nt = 0; nt < 8; ++nt)
#pragma unroll
    for (int r = 0; r < 16; ++r) acc[nt][r] = 0.f;
  float m = -__builtin_inff(), l = 0.f;

  const int s_begin = ns * CHUNK_;
  for (int it = 0; it < CHUNK_ / 64; ++it) {
    const int s0 = s_begin + it * 64;
    // ---- QK^T: two 32-row s-tiles, K=256 (16 ksteps), 3-term hi/lo
    const size_t eb = (((size_t)b * TE_) + s0 + ln) * H_ + hi * 8;
    fx16 sa0, sa1;
#pragma unroll
    for (int r = 0; r < 16; ++r) { sa0[r] = 0.f; sa1[r] = 0.f; }
#pragma unroll
    for (int kk = 0; kk < 16; ++kk) {
      const s16x8 ah0 = *(const s16x8*)(ehi + eb + kk * 16);
      const s16x8 al0 = *(const s16x8*)(elo + eb + kk * 16);
      const s16x8 ah1 = *(const s16x8*)(ehi + eb + (size_t)32 * H_ + kk * 16);
      const s16x8 al1 = *(const s16x8*)(elo + eb + (size_t)32 * H_ + kk * 16);
      const s16x8 bh = *(const s16x8*)(dh + db + kk * 16);
      const s16x8 bl = *(const s16x8*)(dl + db + kk * 16);
      sa0 = MFMA32(ah0, bh, sa0);
      sa0 = MFMA32(al0, bh, sa0);
      sa0 = MFMA32(ah0, bl, sa0);
      sa1 = MFMA32(ah1, bh, sa1);
      sa1 = MFMA32(al1, bh, sa1);
      sa1 = MFMA32(ah1, bl, sa1);
    }

    // ---- online softmax over 64 kv rows (own 32 + partner lane^32)
    float mx = -__builtin_inff();
#pragma unroll
    for (int r = 0; r < 16; ++r) mx = fmaxf(mx, fmaxf(sa0[r], sa1[r]));
    mx = fmaxf(mx, __shfl_xor(mx, 32, 64));
    if (!__all(mx <= m + 4.0f)) {      // defer-max
      const float nm = fmaxf(m, mx);
      const float sc = __expf(m - nm);
      m = nm; l *= sc;
#pragma unroll
      for (int nt = 0; nt < 8; ++nt)
#pragma unroll
        for (int r = 0; r < 16; ++r) acc[nt][r] *= sc;
    }
    unsigned pku[4][4];                // packed bf16 P per kstep
    float rs = 0.f;
    {
      float t[16];
#pragma unroll
      for (int r = 0; r < 16; ++r) {
        const float p = __expf(sa0[r] - m);
        t[r] = __uint_as_float(__float_as_uint(p) & 0xFFFF0000u);
        rs += t[r];
      }
#pragma unroll
      for (int h2 = 0; h2 < 2; ++h2) {
        const int o = h2 * 8;
        pku[h2][0] = pk2(t[o + 0], t[o + 1]);
        pku[h2][1] = pk2(t[o + 2], t[o + 3]);
        pku[h2][2] = pk2(t[o + 4], t[o + 5]);
        pku[h2][3] = pk2(t[o + 6], t[o + 7]);
      }
#pragma unroll
      for (int r = 0; r < 16; ++r) {
        const float p = __expf(sa1[r] - m);
        t[r] = __uint_as_float(__float_as_uint(p) & 0xFFFF0000u);
        rs += t[r];
      }
#pragma unroll
      for (int h2 = 0; h2 < 2; ++h2) {
        const int o = h2 * 8;
        pku[2 + h2][0] = pk2(t[o + 0], t[o + 1]);
        pku[2 + h2][1] = pk2(t[o + 2], t[o + 3]);
        pku[2 + h2][2] = pk2(t[o + 4], t[o + 5]);
        pku[2 + h2][3] = pk2(t[o + 6], t[o + 7]);
      }
    }
    rs += __shfl_xor(rs, 32, 64);
    l += rs;

    // ---- PV: 4 ksteps x 8 h-tiles; B-frag assembled via one lane-pair swap
    const size_t tb2 = (((size_t)b * H_) + ln) * TE_ + s0 + hi * 8;
#pragma unroll
    for (int ks = 0; ks < 4; ++ks) {
      const unsigned P0 = pku[ks][0], P1 = pku[ks][1];
      const unsigned P2 = pku[ks][2], P3 = pku[ks][3];
      const unsigned x0 = hi ? P0 : P2;
      const unsigned x1 = hi ? P1 : P3;
      const unsigned r0 = __shfl_xor(x0, 32, 64);
      const unsigned r1 = __shfl_xor(x1, 32, 64);
      union { unsigned u[4]; s16x8 v; } pf;
      pf.u[0] = hi ? r0 : P0; pf.u[1] = hi ? r1 : P1;
      pf.u[2] = hi ? P2 : r0; pf.u[3] = hi ? P3 : r1;
#pragma unroll
      for (int nt = 0; nt < 8; ++nt) {
        const s16x8 ea = *(const s16x8*)(eT + tb2 + (size_t)nt * 32 * TE_ + ks * 16);
        acc[nt] = MFMA32(ea, pf.v, acc[nt]);
      }
    }
  }

  // ---- write bf16 partials: pacc[ns][R][h]; (m,l) once per q
  unsigned short* pr = pacc + (((size_t)ns * NROW_) + R) * H_;
#pragma unroll
  for (int nt = 0; nt < 8; ++nt) {
#pragma unroll
    for (int qd = 0; qd < 4; ++qd) {
      u16x4 o;
#pragma unroll
      for (int j = 0; j < 4; ++j) o[j] = f2bf(acc[nt][qd * 4 + j]);
      *(u16x4*)(pr + nt * 32 + qd * 8 + hi * 4) = o;
    }
  }
  if (hi == 0) {
    pm[ns * NROW_ + R] = m;
    pl[ns * NROW_ + R] = l;
  }
}

// ---------------- dense2: combine NS partials -> X=[value,d] bf16 -> MFMA -> tanh
__global__ __launch_bounds__(256) void dense2(const unsigned short* __restrict__ pacc,
                                              const float* __restrict__ pm,
                                              const float* __restrict__ pl,
                                              const float* __restrict__ dmat,
                                              const unsigned short* __restrict__ WT,
                                              const float* __restrict__ bias,
                                              float* __restrict__ out) {
  const int row0 = blockIdx.x * 32;    // 256 blocks
  const int tid = threadIdx.x;
  const int w = tid >> 6;
  const int lane = tid & 63;
  const int ln = lane & 31, hi = lane >> 5;
  __shared__ unsigned short Xl[32][520];

  // ---- stage X rows: k<256 combined value (bf16), k>=256 d (bf16)
  {
    const int row = tid >> 3;
    const int c0 = (tid & 7) * 32;
    const int R = row0 + row;
    float wts[NS_];
    float M = -__builtin_inff();
#pragma unroll
    for (int s = 0; s < NS_; ++s) M = fmaxf(M, pm[s * NROW_ + R]);
    float L = 0.f;
#pragma unroll
    for (int s = 0; s < NS_; ++s) {
      wts[s] = __expf(pm[s * NROW_ + R] - M);
      L += wts[s] * pl[s * NROW_ + R];
    }
    const float inv = 1.0f / L;
#pragma unroll
    for (int c8 = 0; c8 < 4; ++c8) {
      const int cc = c0 + c8 * 8;
      float o8[8];
#pragma unroll
      for (int j = 0; j < 8; ++j) o8[j] = 0.f;
#pragma unroll
      for (int s = 0; s < NS_; ++s) {
        const s16x8 v = *(const s16x8*)&pacc[(((size_t)s * NROW_) + R) * H_ + cc];
#pragma unroll
        for (int j = 0; j < 8; ++j)
          o8[j] += wts[s] * bf2f((unsigned short)v[j]);
      }
      u16x4 y0, y1;
#pragma unroll
      for (int j = 0; j < 4; ++j) {
        y0[j] = f2bf(o8[j] * inv);
        y1[j] = f2bf(o8[4 + j] * inv);
      }
      *(u16x4*)&Xl[row][cc] = y0;
      *(u16x4*)&Xl[row][cc + 4] = y1;
    }
    // d part -> k 256..511
    const float* drow = dmat + (size_t)R * H_ + c0;
#pragma unroll
    for (int c8 = 0; c8 < 8; ++c8) {
      const fx4 v = *(const fx4*)&drow[c8 * 4];
      u16x4 y;
#pragma unroll
      for (int j = 0; j < 4; ++j) y[j] = f2bf(v[j]);
      *(u16x4*)&Xl[row][256 + c0 + c8 * 4] = y;
    }
  }
  __syncthreads();

  // ---- GEMM: per wave 2 n-tiles, K=512 (32 ksteps)
  fx16 a0, a1;
#pragma unroll
  for (int r = 0; r < 16; ++r) { a0[r] = 0.f; a1[r] = 0.f; }
  const int n0 = w * 64;
#pragma unroll
  for (int ks = 0; ks < 32; ++ks) {
    const s16x8 av = *(const s16x8*)&Xl[ln][ks * 16 + hi * 8];
    const s16x8 b0 = *(const s16x8*)(WT + (size_t)(n0 + ln) * 512 + ks * 16 + hi * 8);
    const s16x8 b1 = *(const s16x8*)(WT + (size_t)(n0 + 32 + ln) * 512 + ks * 16 + hi * 8);
    a0 = MFMA32(av, b0, a0);
    a1 = MFMA32(av, b1, a1);
  }
  // ---- epilogue: tanh(acc + bias), coalesced b32 stores
  const float bn0 = bias[n0 + ln];
  const float bn1 = bias[n0 + 32 + ln];
#pragma unroll
  for (int r = 0; r < 16; ++r) {
    const int rloc = (r & 3) + 8 * (r >> 2) + 4 * hi;
    const size_t ro = (size_t)(row0 + rloc) * 256;
    out[ro + n0 + ln] = tanhf(a0[r] + bn0);
    out[ro + n0 + 32 + ln] = tanhf(a1[r] + bn1);
  }
}

extern "C" void kernel_launch(void* const* d_in, const int* in_sizes, int n_in,
                              void* d_out, int out_size, void* d_ws, size_t ws_size,
                              hipStream_t stream) {
  const float* e = (const float*)d_in[0];    // [8,4096,256]
  const float* d = (const float*)d_in[1];    // [8,1024,256]
  const float* W = (const float*)d_in[2];    // [512,256]
  const float* bias = (const float*)d_in[3]; // [256]
  float* out = (float*)d_out;

  char* p = (char*)d_ws;
  const size_t EB = (size_t)B_ * TE_ * H_ * 2;       // 16 MiB
  const size_t DB = (size_t)B_ * TD_ * H_ * 2;       // 4 MiB
  const size_t WB = (size_t)512 * 256 * 2;           // 256 KiB
  const size_t PB = (size_t)NS_ * NROW_ * H_ * 2;    // 32 MiB
  unsigned short* ehi = (unsigned short*)p;            p += EB;
  unsigned short* elo = (unsigned short*)p;            p += EB;
  unsigned short* eT  = (unsigned short*)p;            p += EB;
  unsigned short* dh  = (unsigned short*)p;            p += DB;
  unsigned short* dl  = (unsigned short*)p;            p += DB;
  unsigned short* WT  = (unsigned short*)p;            p += WB;
  unsigned short* pacc = (unsigned short*)p;           p += PB;
  float* pmv = (float*)p;                              p += (size_t)NS_ * NROW_ * 4;
  float* plv = (float*)p;

  prep_e<<<dim3(2048), dim3(256), 0, stream>>>(e, ehi, elo, eT);
  prep_dw<<<dim3(1152), dim3(256), 0, stream>>>(d, W, dh, dl, WT);
  flash3<<<dim3(512), dim3(256), 0, stream>>>(ehi, elo, eT, dh, dl, pacc, pmv, plv);
  dense2<<<dim3(256), dim3(256), 0, stream>>>(pacc, pmv, plv, d, WT, bias, out);
}

// Round 4
// 183.170 us; speedup vs baseline: 1.5994x; 1.5994x over previous
//
#include <hip/hip_runtime.h>

// Attention_Layer: scores=d@e^T -> softmax -> value=attn@e -> tanh([value,d]@W+b)
// B=8 TE=4096 TD=1024 H=256 NH=256, f32 in/out.
// Round 4: round-2 flash structure + precomputed bf16 hi/lo (no in-loop VALU
// conversion), global_load_lds staging with pre-swizzled sources (conflict-free
// ds_read), NS=8 with XCD-aligned chunks, 3 blocks/CU, RNE P, bf16 partials,
// fused combine+dense MFMA epilogue.

#define B_ 8
#define TE_ 4096
#define TD_ 1024
#define H_ 256
#define NS_ 8
#define CHUNK_ (TE_ / NS_)   // 512
#define NROW_ (B_ * TD_)     // 8192

typedef __attribute__((ext_vector_type(8))) short s16x8;
typedef __attribute__((ext_vector_type(4))) float fx4;
typedef __attribute__((ext_vector_type(16))) float fx16;
typedef __attribute__((ext_vector_type(4))) unsigned short u16x4;

#define MFMA(a, b, c) __builtin_amdgcn_mfma_f32_16x16x32_bf16(a, b, c, 0, 0, 0)
#define MFMA32(a, b, c) __builtin_amdgcn_mfma_f32_32x32x16_bf16(a, b, c, 0, 0, 0)

__device__ __forceinline__ unsigned short f2bf(float x) {
  unsigned u = __float_as_uint(x);
  unsigned r = (u + 0x7fffu + ((u >> 16) & 1u)) >> 16;  // RNE
  return (unsigned short)r;
}
__device__ __forceinline__ float bf2f(unsigned short s) {
  return __uint_as_float(((unsigned)s) << 16);
}
// pack two bf16-representable f32 into one u32 (lo = f0, hi = f1)
__device__ __forceinline__ unsigned pk2(float f0, float f1) {
  return (__float_as_uint(f0) >> 16) | (__float_as_uint(f1) & 0xFFFF0000u);
}
__device__ __forceinline__ void gload_lds16(const void* g, void* l) {
  __builtin_amdgcn_global_load_lds(
      (const __attribute__((address_space(1))) void*)g,
      (__attribute__((address_space(3))) void*)l, 16, 0, 0);
}

// ---------------- prep: e -> ehi(RNE)/elo(resid)/eT ; W -> WT [256n][512k]
__global__ __launch_bounds__(256) void prep(const float* __restrict__ e,
                                            const float* __restrict__ W,
                                            unsigned short* __restrict__ ehi,
                                            unsigned short* __restrict__ elo,
                                            unsigned short* __restrict__ eT,
                                            unsigned short* __restrict__ WT) {
  __shared__ unsigned short lt[64][65];
  __shared__ float wl[32][33];
  const int bid = blockIdx.x;
  const int tid = threadIdx.x;
  if (bid < 2048) {                   // e part: 8 * 64 * 4 tiles
    const int b = bid >> 8;
    const int s0 = ((bid >> 2) & 63) * 64;
    const int h0 = (bid & 3) * 64;
#pragma unroll
    for (int i = 0; i < 4; ++i) {
      const int row = (tid >> 4) + 16 * i;
      const int col = (tid & 15) * 4;
      const size_t go = (((size_t)b * TE_) + s0 + row) * H_ + h0 + col;
      const fx4 v = *(const fx4*)&e[go];
      u16x4 hv, lv;
#pragma unroll
      for (int j = 0; j < 4; ++j) {
        const unsigned short hb = f2bf(v[j]);
        hv[j] = hb;
        lv[j] = f2bf(v[j] - bf2f(hb));
        lt[row][col + j] = hb;
      }
      *(u16x4*)&ehi[go] = hv;
      *(u16x4*)&elo[go] = lv;
    }
    __syncthreads();
#pragma unroll
    for (int i = 0; i < 2; ++i) {
      const int idx = tid + 256 * i;
      const int hh = idx >> 3;
      const int sc = (idx & 7) * 8;
      s16x8 v;
#pragma unroll
      for (int j = 0; j < 8; ++j) v[j] = (short)lt[sc + j][hh];
      *(s16x8*)&eT[(((size_t)b * H_) + h0 + hh) * TE_ + s0 + sc] = v;
    }
  } else {                            // W part: 128 tiles of 32x32
    const int tb = bid - 2048;
    const int k0 = (tb >> 3) * 32, n0 = (tb & 7) * 32;
    const int r = tid >> 3, c4 = (tid & 7) * 4;
    const fx4 v = *(const fx4*)&W[(size_t)(k0 + r) * 256 + n0 + c4];
#pragma unroll
    for (int j = 0; j < 4; ++j) wl[r][c4 + j] = v[j];
    __syncthreads();
    u16x4 o;
#pragma unroll
    for (int j = 0; j < 4; ++j) o[j] = f2bf(wl[c4 + j][r]);
    *(u16x4*)&WT[(size_t)(n0 + r) * 512 + k0 + c4] = o;
  }
}

// ---------------- flash4: 1024 blocks = ns(8)|qb(16)|b(8); 4 waves x 16 q
__global__ __launch_bounds__(256, 3) void flash4(
    const unsigned short* __restrict__ ehi_g, const unsigned short* __restrict__ elo_g,
    const unsigned short* __restrict__ eT_g, const float* __restrict__ dmat,
    unsigned short* __restrict__ pacc, float* __restrict__ pm,
    float* __restrict__ pl) {
  const int bid = blockIdx.x;
  const int ns = bid & 7;             // XCD-aligned: blocks sharing a chunk co-locate
  const int qb = (bid >> 3) & 15;
  const int b = bid >> 7;
  const int tid = threadIdx.x;
  const int w = tid >> 6;
  const int lane = tid & 63;
  const int g = lane >> 4, c = lane & 15;
  const int qrow = qb * 64 + w * 16 + c;

  __shared__ uint4 ehi_l[1024];       // [32 s][32 chunk16B], chunk XOR (s&7)
  __shared__ uint4 elo_l[1024];
  __shared__ uint4 etl_l[1024];       // [256 h][4 chunk16B], linear (conflict-free)

  // ---- d B-frags hi/lo in registers (once per kernel)
  s16x8 bd_h[8], bd_l[8];
  {
    const float* dr = dmat + ((size_t)b * TD_ + qrow) * H_;
#pragma unroll
    for (int kk = 0; kk < 8; ++kk) {
      const fx4 x0 = *(const fx4*)&dr[kk * 32 + g * 8];
      const fx4 x1 = *(const fx4*)&dr[kk * 32 + g * 8 + 4];
      s16x8 hh, ll;
#pragma unroll
      for (int j = 0; j < 4; ++j) {
        unsigned short hb = f2bf(x0[j]);
        hh[j] = (short)hb; ll[j] = (short)f2bf(x0[j] - bf2f(hb));
        hb = f2bf(x1[j]);
        hh[4 + j] = (short)hb; ll[4 + j] = (short)f2bf(x1[j] - bf2f(hb));
      }
      bd_h[kk] = hh; bd_l[kk] = ll;
    }
  }

  fx4 acc[16];
#pragma unroll
  for (int nt = 0; nt < 16; ++nt) acc[nt] = (fx4){0.f, 0.f, 0.f, 0.f};
  float m = -__builtin_inff(), l = 0.f;
  const int xr = c & 7;

  for (int it = 0; it < CHUNK_ / 32; ++it) {   // 16 iters
    const int s0 = ns * CHUNK_ + it * 32;
    // ---- stage via global_load_lds (pre-swizzled e source; linear eT)
    const size_t ebase = ((size_t)b * TE_ + s0) * H_;
    const size_t tbase = (size_t)b * H_ * TE_ + s0;
#pragma unroll
    for (int i = 0; i < 4; ++i) {
      const int L = tid + 256 * i;    // 0..1023
      const int s = L >> 5, ch = L & 31;
      const int col = (ch ^ (s & 7)) * 8;
      gload_lds16(ehi_g + ebase + s * H_ + col, &ehi_l[L]);
      gload_lds16(elo_g + ebase + s * H_ + col, &elo_l[L]);
      const int h = L >> 2, sc = (L & 3) * 8;
      gload_lds16(eT_g + tbase + (size_t)h * TE_ + sc, &etl_l[L]);
    }
    __syncthreads();

    // ---- QK^T (swapped): S^T[s][q] = e(A, LDS) x d(B, regs), 3-term hi/lo
    fx4 sa0 = (fx4){0.f, 0.f, 0.f, 0.f};
    fx4 sa1 = (fx4){0.f, 0.f, 0.f, 0.f};
#pragma unroll
    for (int kk = 0; kk < 8; ++kk) {
      const int sl = (kk * 4 + g) ^ xr;
      const s16x8 ah0 = *(const s16x8*)&ehi_l[c * 32 + sl];
      const s16x8 al0 = *(const s16x8*)&elo_l[c * 32 + sl];
      const s16x8 ah1 = *(const s16x8*)&ehi_l[(16 + c) * 32 + sl];
      const s16x8 al1 = *(const s16x8*)&elo_l[(16 + c) * 32 + sl];
      sa0 = MFMA(ah0, bd_h[kk], sa0);
      sa0 = MFMA(al0, bd_h[kk], sa0);
      sa0 = MFMA(ah0, bd_l[kk], sa0);
      sa1 = MFMA(ah1, bd_h[kk], sa1);
      sa1 = MFMA(al1, bd_h[kk], sa1);
      sa1 = MFMA(ah1, bd_l[kk], sa1);
    }

    // ---- online softmax (q=c lives on 4 g-lanes: 2 shfl rounds)
    float mx = fmaxf(fmaxf(fmaxf(sa0[0], sa0[1]), fmaxf(sa0[2], sa0[3])),
                     fmaxf(fmaxf(sa1[0], sa1[1]), fmaxf(sa1[2], sa1[3])));
    mx = fmaxf(mx, __shfl_xor(mx, 16, 64));
    mx = fmaxf(mx, __shfl_xor(mx, 32, 64));
    if (!__all(mx <= m + 4.0f)) {      // defer-max
      const float nm = fmaxf(m, mx);
      const float sc = __expf(m - nm);
      m = nm; l *= sc;
#pragma unroll
      for (int nt = 0; nt < 16; ++nt) {
#pragma unroll
        for (int r = 0; r < 4; ++r) acc[nt][r] *= sc;
      }
    }
    float t0[4], t1[4];
    float rs = 0.f;
#pragma unroll
    for (int r = 0; r < 4; ++r) {
      t0[r] = bf2f(f2bf(__expf(sa0[r] - m)));   // RNE bf16-rounded P
      t1[r] = bf2f(f2bf(__expf(sa1[r] - m)));
      rs += t0[r] + t1[r];                      // l matches bf16 P exactly
    }
    rs += __shfl_xor(rs, 16, 64);
    rs += __shfl_xor(rs, 32, 64);
    l += rs;

    // ---- pack P^T bf16, gather PV B-frags via shfl (round-2 verified)
    const unsigned pk00 = pk2(t0[0], t0[1]);
    const unsigned pk01 = pk2(t0[2], t0[3]);
    const unsigned pk10 = pk2(t1[0], t1[1]);
    const unsigned pk11 = pk2(t1[2], t1[3]);
    const int src0 = ((g & 1) << 5) + c;
    const int src1 = src0 + 16;
    const unsigned a0 = __shfl(pk00, src0, 64);
    const unsigned a1 = __shfl(pk01, src0, 64);
    const unsigned a2 = __shfl(pk00, src1, 64);
    const unsigned a3 = __shfl(pk01, src1, 64);
    const unsigned b0 = __shfl(pk10, src0, 64);
    const unsigned b1 = __shfl(pk11, src0, 64);
    const unsigned b2 = __shfl(pk10, src1, 64);
    const unsigned b3 = __shfl(pk11, src1, 64);
    const bool hiT = (g >= 2);
    union { unsigned u[4]; s16x8 v; } pb;
    pb.u[0] = hiT ? b0 : a0; pb.u[1] = hiT ? b1 : a1;
    pb.u[2] = hiT ? b2 : a2; pb.u[3] = hiT ? b3 : a3;

    // ---- PV: value^T[h][q] += eT(A, LDS linear) x P^T(B)
#pragma unroll
    for (int nt = 0; nt < 16; ++nt) {
      const s16x8 ea = *(const s16x8*)&etl_l[(nt * 16 + c) * 4 + g];
      acc[nt] = MFMA(ea, pb.v, acc[nt]);
    }
    __syncthreads();
  }

  // ---- bf16 partials (unnormalized) + (m,l) per q
  const size_t R = (size_t)b * TD_ + qrow;
  unsigned short* pr = pacc + (((size_t)ns * NROW_) + R) * H_;
#pragma unroll
  for (int nt = 0; nt < 16; ++nt) {
    u16x4 o;
#pragma unroll
    for (int j = 0; j < 4; ++j) o[j] = f2bf(acc[nt][j]);
    *(u16x4*)(pr + nt * 16 + g * 4) = o;
  }
  if (g == 0) {
    pm[ns * NROW_ + R] = m;
    pl[ns * NROW_ + R] = l;
  }
}

// ---------------- dense2: combine NS partials -> X=[value,d] bf16 -> MFMA -> tanh
__global__ __launch_bounds__(256) void dense2(const unsigned short* __restrict__ pacc,
                                              const float* __restrict__ pm,
                                              const float* __restrict__ pl,
                                              const float* __restrict__ dmat,
                                              const unsigned short* __restrict__ WT,
                                              const float* __restrict__ bias,
                                              float* __restrict__ out) {
  const int row0 = blockIdx.x * 32;    // 256 blocks
  const int tid = threadIdx.x;
  const int w = tid >> 6;
  const int lane = tid & 63;
  const int ln = lane & 31, hi = lane >> 5;
  __shared__ unsigned short Xl[32][520];

  {
    const int row = tid >> 3;
    const int c0 = (tid & 7) * 32;
    const int R = row0 + row;
    float wts[NS_];
    float M = -__builtin_inff();
#pragma unroll
    for (int s = 0; s < NS_; ++s) M = fmaxf(M, pm[s * NROW_ + R]);
    float L = 0.f;
#pragma unroll
    for (int s = 0; s < NS_; ++s) {
      wts[s] = __expf(pm[s * NROW_ + R] - M);
      L += wts[s] * pl[s * NROW_ + R];
    }
    const float inv = 1.0f / L;
#pragma unroll
    for (int c8 = 0; c8 < 4; ++c8) {
      const int cc = c0 + c8 * 8;
      float o8[8];
#pragma unroll
      for (int j = 0; j < 8; ++j) o8[j] = 0.f;
#pragma unroll
      for (int s = 0; s < NS_; ++s) {
        const s16x8 v = *(const s16x8*)&pacc[(((size_t)s * NROW_) + R) * H_ + cc];
#pragma unroll
        for (int j = 0; j < 8; ++j)
          o8[j] += wts[s] * bf2f((unsigned short)v[j]);
      }
      u16x4 y0, y1;
#pragma unroll
      for (int j = 0; j < 4; ++j) {
        y0[j] = f2bf(o8[j] * inv);
        y1[j] = f2bf(o8[4 + j] * inv);
      }
      *(u16x4*)&Xl[row][cc] = y0;
      *(u16x4*)&Xl[row][cc + 4] = y1;
    }
    const float* drow = dmat + (size_t)R * H_ + c0;
#pragma unroll
    for (int c8 = 0; c8 < 8; ++c8) {
      const fx4 v = *(const fx4*)&drow[c8 * 4];
      u16x4 y;
#pragma unroll
      for (int j = 0; j < 4; ++j) y[j] = f2bf(v[j]);
      *(u16x4*)&Xl[row][256 + c0 + c8 * 4] = y;
    }
  }
  __syncthreads();

  fx16 a0, a1;
#pragma unroll
  for (int r = 0; r < 16; ++r) { a0[r] = 0.f; a1[r] = 0.f; }
  const int n0 = w * 64;
#pragma unroll
  for (int ks = 0; ks < 32; ++ks) {
    const s16x8 av = *(const s16x8*)&Xl[ln][ks * 16 + hi * 8];
    const s16x8 b0 = *(const s16x8*)(WT + (size_t)(n0 + ln) * 512 + ks * 16 + hi * 8);
    const s16x8 b1 = *(const s16x8*)(WT + (size_t)(n0 + 32 + ln) * 512 + ks * 16 + hi * 8);
    a0 = MFMA32(av, b0, a0);
    a1 = MFMA32(av, b1, a1);
  }
  const float bn0 = bias[n0 + ln];
  const float bn1 = bias[n0 + 32 + ln];
#pragma unroll
  for (int r = 0; r < 16; ++r) {
    const int rloc = (r & 3) + 8 * (r >> 2) + 4 * hi;
    const size_t ro = (size_t)(row0 + rloc) * 256;
    out[ro + n0 + ln] = tanhf(a0[r] + bn0);
    out[ro + n0 + 32 + ln] = tanhf(a1[r] + bn1);
  }
}

extern "C" void kernel_launch(void* const* d_in, const int* in_sizes, int n_in,
                              void* d_out, int out_size, void* d_ws, size_t ws_size,
                              hipStream_t stream) {
  const float* e = (const float*)d_in[0];    // [8,4096,256]
  const float* d = (const float*)d_in[1];    // [8,1024,256]
  const float* W = (const float*)d_in[2];    // [512,256]
  const float* bias = (const float*)d_in[3]; // [256]
  float* out = (float*)d_out;

  char* p = (char*)d_ws;
  const size_t EB = (size_t)B_ * TE_ * H_ * 2;       // 16 MiB
  const size_t WB = (size_t)512 * 256 * 2;           // 256 KiB
  const size_t PB = (size_t)NS_ * NROW_ * H_ * 2;    // 32 MiB (bf16 partials)
  unsigned short* ehi = (unsigned short*)p;            p += EB;
  unsigned short* elo = (unsigned short*)p;            p += EB;
  unsigned short* eT  = (unsigned short*)p;            p += EB;
  unsigned short* WT  = (unsigned short*)p;            p += WB;
  unsigned short* pacc = (unsigned short*)p;           p += PB;
  float* pmv = (float*)p;                              p += (size_t)NS_ * NROW_ * 4;
  float* plv = (float*)p;                              // total ~84.6 MiB

  prep<<<dim3(2176), dim3(256), 0, stream>>>(e, W, ehi, elo, eT, WT);
  flash4<<<dim3(1024), dim3(256), 0, stream>>>(ehi, elo, eT, d, pacc, pmv, plv);
  dense2<<<dim3(256), dim3(256), 0, stream>>>(pacc, pmv, plv, d, WT, bias, out);
}

// Round 5
// 132.524 us; speedup vs baseline: 2.2106x; 1.3822x over previous
//
#include <hip/hip_runtime.h>

// Attention_Layer: scores=d@e^T -> softmax -> value=attn@e -> tanh([value,d]@W+b)
// B=8 TE=4096 TD=1024 H=256 NH=256, f32 in/out.
// Round 5: double-buffered gload_lds staging (prefetch next tile before compute,
// one __syncthreads per iter drains already-landed loads), conflict-free PV LDS
// layout [nt][g][c], 8 waves x 16q = 128 q/block, loop-invariant staging ptrs.

#define B_ 8
#define TE_ 4096
#define TD_ 1024
#define H_ 256
#define NS_ 8
#define CHUNK_ (TE_ / NS_)   // 512
#define NIT_ (CHUNK_ / 32)   // 16
#define NROW_ (B_ * TD_)     // 8192

typedef __attribute__((ext_vector_type(8))) short s16x8;
typedef __attribute__((ext_vector_type(4))) float fx4;
typedef __attribute__((ext_vector_type(16))) float fx16;
typedef __attribute__((ext_vector_type(4))) unsigned short u16x4;

#define MFMA(a, b, c) __builtin_amdgcn_mfma_f32_16x16x32_bf16(a, b, c, 0, 0, 0)
#define MFMA32(a, b, c) __builtin_amdgcn_mfma_f32_32x32x16_bf16(a, b, c, 0, 0, 0)

__device__ __forceinline__ unsigned short f2bf(float x) {
  unsigned u = __float_as_uint(x);
  unsigned r = (u + 0x7fffu + ((u >> 16) & 1u)) >> 16;  // RNE
  return (unsigned short)r;
}
__device__ __forceinline__ float bf2f(unsigned short s) {
  return __uint_as_float(((unsigned)s) << 16);
}
// pack two bf16-representable f32 into one u32 (lo = f0, hi = f1)
__device__ __forceinline__ unsigned pk2(float f0, float f1) {
  return (__float_as_uint(f0) >> 16) | (__float_as_uint(f1) & 0xFFFF0000u);
}
__device__ __forceinline__ void gload_lds16(const void* g, void* l) {
  __builtin_amdgcn_global_load_lds(
      (const __attribute__((address_space(1))) void*)g,
      (__attribute__((address_space(3))) void*)l, 16, 0, 0);
}

// ---------------- prep: e -> ehi(RNE)/elo(resid)/eT ; W -> WT [256n][512k]
__global__ __launch_bounds__(256) void prep(const float* __restrict__ e,
                                            const float* __restrict__ W,
                                            unsigned short* __restrict__ ehi,
                                            unsigned short* __restrict__ elo,
                                            unsigned short* __restrict__ eT,
                                            unsigned short* __restrict__ WT) {
  __shared__ unsigned short lt[64][65];
  __shared__ float wl[32][33];
  const int bid = blockIdx.x;
  const int tid = threadIdx.x;
  if (bid < 2048) {                   // e part: 8 * 64 * 4 tiles
    const int b = bid >> 8;
    const int s0 = ((bid >> 2) & 63) * 64;
    const int h0 = (bid & 3) * 64;
#pragma unroll
    for (int i = 0; i < 4; ++i) {
      const int row = (tid >> 4) + 16 * i;
      const int col = (tid & 15) * 4;
      const size_t go = (((size_t)b * TE_) + s0 + row) * H_ + h0 + col;
      const fx4 v = *(const fx4*)&e[go];
      u16x4 hv, lv;
#pragma unroll
      for (int j = 0; j < 4; ++j) {
        const unsigned short hb = f2bf(v[j]);
        hv[j] = hb;
        lv[j] = f2bf(v[j] - bf2f(hb));
        lt[row][col + j] = hb;
      }
      *(u16x4*)&ehi[go] = hv;
      *(u16x4*)&elo[go] = lv;
    }
    __syncthreads();
#pragma unroll
    for (int i = 0; i < 2; ++i) {
      const int idx = tid + 256 * i;
      const int hh = idx >> 3;
      const int sc = (idx & 7) * 8;
      s16x8 v;
#pragma unroll
      for (int j = 0; j < 8; ++j) v[j] = (short)lt[sc + j][hh];
      *(s16x8*)&eT[(((size_t)b * H_) + h0 + hh) * TE_ + s0 + sc] = v;
    }
  } else {                            // W part: 128 tiles of 32x32
    const int tb = bid - 2048;
    const int k0 = (tb >> 3) * 32, n0 = (tb & 7) * 32;
    const int r = tid >> 3, c4 = (tid & 7) * 4;
    const fx4 v = *(const fx4*)&W[(size_t)(k0 + r) * 256 + n0 + c4];
#pragma unroll
    for (int j = 0; j < 4; ++j) wl[r][c4 + j] = v[j];
    __syncthreads();
    u16x4 o;
#pragma unroll
    for (int j = 0; j < 4; ++j) o[j] = f2bf(wl[c4 + j][r]);
    *(u16x4*)&WT[(size_t)(n0 + r) * 512 + k0 + c4] = o;
  }
}

// ---------------- flash5: 512 blocks = b(8)|qb(8)|ns(8); 8 waves x 16 q
__global__ __launch_bounds__(512, 2) void flash5(
    const unsigned short* __restrict__ ehi_g, const unsigned short* __restrict__ elo_g,
    const unsigned short* __restrict__ eT_g, const float* __restrict__ dmat,
    unsigned short* __restrict__ pacc, float* __restrict__ pm,
    float* __restrict__ pl) {
  const int bid = blockIdx.x;
  const int ns = bid & 7;             // XCD-aligned chunk sharing
  const int qb = (bid >> 3) & 7;
  const int b = bid >> 6;
  const int tid = threadIdx.x;
  const int w = tid >> 6;
  const int lane = tid & 63;
  const int g = lane >> 4, c = lane & 15;
  const int qrow = qb * 128 + w * 16 + c;

  __shared__ uint4 smem[2][3][1024];  // 96 KB: dbuf x {ehi, elo, eT}

  // ---- loop-invariant staging source pointers (advance per staged tile)
  const unsigned short *peh0, *peh1, *pel0, *pel1, *pet0, *pet1;
  {
    const size_t ebase = ((size_t)b * TE_ + ns * CHUNK_) * H_;
    const size_t tbase = (size_t)b * H_ * TE_ + ns * CHUNK_;
    int L = tid;
    int s = L >> 5, ch = L & 31;
    peh0 = ehi_g + ebase + s * H_ + (ch ^ (s & 7)) * 8;
    pel0 = elo_g + ebase + s * H_ + (ch ^ (s & 7)) * 8;
    int h2 = (L >> 6) * 16 + (L & 15), sc = ((L >> 4) & 3) * 8;
    pet0 = eT_g + tbase + (size_t)h2 * TE_ + sc;
    L = tid + 512;
    s = L >> 5; ch = L & 31;
    peh1 = ehi_g + ebase + s * H_ + (ch ^ (s & 7)) * 8;
    pel1 = elo_g + ebase + s * H_ + (ch ^ (s & 7)) * 8;
    h2 = (L >> 6) * 16 + (L & 15); sc = ((L >> 4) & 3) * 8;
    pet1 = eT_g + tbase + (size_t)h2 * TE_ + sc;
  }
  auto STAGE = [&](int buf) {
    uint4* eh = smem[buf][0];
    uint4* el = smem[buf][1];
    uint4* et = smem[buf][2];
    gload_lds16(peh0, &eh[tid]);
    gload_lds16(peh1, &eh[tid + 512]);
    gload_lds16(pel0, &el[tid]);
    gload_lds16(pel1, &el[tid + 512]);
    gload_lds16(pet0, &et[tid]);
    gload_lds16(pet1, &et[tid + 512]);
    peh0 += 32 * H_; peh1 += 32 * H_;
    pel0 += 32 * H_; pel1 += 32 * H_;
    pet0 += 32; pet1 += 32;
  };

  STAGE(0);                           // tile 0 in flight during d-preload

  // ---- d B-frags hi/lo in registers (once)
  s16x8 bd_h[8], bd_l[8];
  {
    const float* dr = dmat + ((size_t)b * TD_ + qrow) * H_;
#pragma unroll
    for (int kk = 0; kk < 8; ++kk) {
      const fx4 x0 = *(const fx4*)&dr[kk * 32 + g * 8];
      const fx4 x1 = *(const fx4*)&dr[kk * 32 + g * 8 + 4];
      s16x8 hh, ll;
#pragma unroll
      for (int j = 0; j < 4; ++j) {
        unsigned short hb = f2bf(x0[j]);
        hh[j] = (short)hb; ll[j] = (short)f2bf(x0[j] - bf2f(hb));
        hb = f2bf(x1[j]);
        hh[4 + j] = (short)hb; ll[4 + j] = (short)f2bf(x1[j] - bf2f(hb));
      }
      bd_h[kk] = hh; bd_l[kk] = ll;
    }
  }

  fx4 acc[16];
#pragma unroll
  for (int nt = 0; nt < 16; ++nt) acc[nt] = (fx4){0.f, 0.f, 0.f, 0.f};
  float m = -__builtin_inff(), l = 0.f;
  const int xr = c & 7;

  __syncthreads();                    // tile 0 resident

  for (int it = 0; it < NIT_; ++it) {
    const int cur = it & 1;
    if (it + 1 < NIT_) STAGE(cur ^ 1);   // prefetch next tile (drained at barrier)

    const uint4* eh = smem[cur][0];
    const uint4* el = smem[cur][1];
    const uint4* et = smem[cur][2];

    // ---- QK^T (swapped): S^T[s][q] = e(A, LDS) x d(B, regs), 3-term hi/lo
    fx4 sa0 = (fx4){0.f, 0.f, 0.f, 0.f};
    fx4 sa1 = (fx4){0.f, 0.f, 0.f, 0.f};
#pragma unroll
    for (int kk = 0; kk < 8; ++kk) {
      const int sl = (kk * 4 + g) ^ xr;
      const s16x8 ah0 = *(const s16x8*)&eh[c * 32 + sl];
      const s16x8 al0 = *(const s16x8*)&el[c * 32 + sl];
      const s16x8 ah1 = *(const s16x8*)&eh[(16 + c) * 32 + sl];
      const s16x8 al1 = *(const s16x8*)&el[(16 + c) * 32 + sl];
      sa0 = MFMA(ah0, bd_h[kk], sa0);
      sa0 = MFMA(al0, bd_h[kk], sa0);
      sa0 = MFMA(ah0, bd_l[kk], sa0);
      sa1 = MFMA(ah1, bd_h[kk], sa1);
      sa1 = MFMA(al1, bd_h[kk], sa1);
      sa1 = MFMA(ah1, bd_l[kk], sa1);
    }

    // ---- online softmax (q=c lives on 4 g-lanes: 2 shfl rounds)
    float mx = fmaxf(fmaxf(fmaxf(sa0[0], sa0[1]), fmaxf(sa0[2], sa0[3])),
                     fmaxf(fmaxf(sa1[0], sa1[1]), fmaxf(sa1[2], sa1[3])));
    mx = fmaxf(mx, __shfl_xor(mx, 16, 64));
    mx = fmaxf(mx, __shfl_xor(mx, 32, 64));
    if (!__all(mx <= m + 4.0f)) {      // defer-max
      const float nm = fmaxf(m, mx);
      const float sc = __expf(m - nm);
      m = nm; l *= sc;
#pragma unroll
      for (int nt = 0; nt < 16; ++nt) {
#pragma unroll
        for (int r = 0; r < 4; ++r) acc[nt][r] *= sc;
      }
    }
    float t0[4], t1[4];
    float rs = 0.f;
#pragma unroll
    for (int r = 0; r < 4; ++r) {
      t0[r] = bf2f(f2bf(__expf(sa0[r] - m)));   // RNE bf16-rounded P
      t1[r] = bf2f(f2bf(__expf(sa1[r] - m)));
      rs += t0[r] + t1[r];                      // l matches bf16 P exactly
    }
    rs += __shfl_xor(rs, 16, 64);
    rs += __shfl_xor(rs, 32, 64);
    l += rs;

    // ---- pack P^T bf16, gather PV B-frags via shfl (validated layout)
    const unsigned pk00 = pk2(t0[0], t0[1]);
    const unsigned pk01 = pk2(t0[2], t0[3]);
    const unsigned pk10 = pk2(t1[0], t1[1]);
    const unsigned pk11 = pk2(t1[2], t1[3]);
    const int src0 = ((g & 1) << 5) + c;
    const int src1 = src0 + 16;
    const unsigned a0 = __shfl(pk00, src0, 64);
    const unsigned a1 = __shfl(pk01, src0, 64);
    const unsigned a2 = __shfl(pk00, src1, 64);
    const unsigned a3 = __shfl(pk01, src1, 64);
    const unsigned b0 = __shfl(pk10, src0, 64);
    const unsigned b1 = __shfl(pk11, src0, 64);
    const unsigned b2 = __shfl(pk10, src1, 64);
    const unsigned b3 = __shfl(pk11, src1, 64);
    const bool hiT = (g >= 2);
    union { unsigned u[4]; s16x8 v; } pb;
    pb.u[0] = hiT ? b0 : a0; pb.u[1] = hiT ? b1 : a1;
    pb.u[2] = hiT ? b2 : a2; pb.u[3] = hiT ? b3 : a3;

    // ---- PV: value^T[h][q] += eT(A, [nt][g][c] layout) x P^T(B)
#pragma unroll
    for (int nt = 0; nt < 16; ++nt) {
      const s16x8 ea = *(const s16x8*)&et[nt * 64 + g * 16 + c];
      acc[nt] = MFMA(ea, pb.v, acc[nt]);
    }
    __syncthreads();                  // drains prefetch; next tile resident
  }

  // ---- bf16 partials (unnormalized) + (m,l) per q
  const size_t R = (size_t)b * TD_ + qrow;
  unsigned short* pr = pacc + (((size_t)ns * NROW_) + R) * H_;
#pragma unroll
  for (int nt = 0; nt < 16; ++nt) {
    u16x4 o;
#pragma unroll
    for (int j = 0; j < 4; ++j) o[j] = f2bf(acc[nt][j]);
    *(u16x4*)(pr + nt * 16 + g * 4) = o;
  }
  if (g == 0) {
    pm[ns * NROW_ + R] = m;
    pl[ns * NROW_ + R] = l;
  }
}

// ---------------- dense2: combine NS partials -> X=[value,d] bf16 -> MFMA -> tanh
__global__ __launch_bounds__(256) void dense2(const unsigned short* __restrict__ pacc,
                                              const float* __restrict__ pm,
                                              const float* __restrict__ pl,
                                              const float* __restrict__ dmat,
                                              const unsigned short* __restrict__ WT,
                                              const float* __restrict__ bias,
                                              float* __restrict__ out) {
  const int row0 = blockIdx.x * 32;    // 256 blocks
  const int tid = threadIdx.x;
  const int w = tid >> 6;
  const int lane = tid & 63;
  const int ln = lane & 31, hi = lane >> 5;
  __shared__ unsigned short Xl[32][520];

  {
    const int row = tid >> 3;
    const int c0 = (tid & 7) * 32;
    const int R = row0 + row;
    float wts[NS_];
    float M = -__builtin_inff();
#pragma unroll
    for (int s = 0; s < NS_; ++s) M = fmaxf(M, pm[s * NROW_ + R]);
    float L = 0.f;
#pragma unroll
    for (int s = 0; s < NS_; ++s) {
      wts[s] = __expf(pm[s * NROW_ + R] - M);
      L += wts[s] * pl[s * NROW_ + R];
    }
    const float inv = 1.0f / L;
#pragma unroll
    for (int c8 = 0; c8 < 4; ++c8) {
      const int cc = c0 + c8 * 8;
      float o8[8];
#pragma unroll
      for (int j = 0; j < 8; ++j) o8[j] = 0.f;
#pragma unroll
      for (int s = 0; s < NS_; ++s) {
        const s16x8 v = *(const s16x8*)&pacc[(((size_t)s * NROW_) + R) * H_ + cc];
#pragma unroll
        for (int j = 0; j < 8; ++j)
          o8[j] += wts[s] * bf2f((unsigned short)v[j]);
      }
      u16x4 y0, y1;
#pragma unroll
      for (int j = 0; j < 4; ++j) {
        y0[j] = f2bf(o8[j] * inv);
        y1[j] = f2bf(o8[4 + j] * inv);
      }
      *(u16x4*)&Xl[row][cc] = y0;
      *(u16x4*)&Xl[row][cc + 4] = y1;
    }
    const float* drow = dmat + (size_t)R * H_ + c0;
#pragma unroll
    for (int c8 = 0; c8 < 8; ++c8) {
      const fx4 v = *(const fx4*)&drow[c8 * 4];
      u16x4 y;
#pragma unroll
      for (int j = 0; j < 4; ++j) y[j] = f2bf(v[j]);
      *(u16x4*)&Xl[row][256 + c0 + c8 * 4] = y;
    }
  }
  __syncthreads();

  fx16 a0, a1;
#pragma unroll
  for (int r = 0; r < 16; ++r) { a0[r] = 0.f; a1[r] = 0.f; }
  const int n0 = w * 64;
#pragma unroll
  for (int ks = 0; ks < 32; ++ks) {
    const s16x8 av = *(const s16x8*)&Xl[ln][ks * 16 + hi * 8];
    const s16x8 b0 = *(const s16x8*)(WT + (size_t)(n0 + ln) * 512 + ks * 16 + hi * 8);
    const s16x8 b1 = *(const s16x8*)(WT + (size_t)(n0 + 32 + ln) * 512 + ks * 16 + hi * 8);
    a0 = MFMA32(av, b0, a0);
    a1 = MFMA32(av, b1, a1);
  }
  const float bn0 = bias[n0 + ln];
  const float bn1 = bias[n0 + 32 + ln];
#pragma unroll
  for (int r = 0; r < 16; ++r) {
    const int rloc = (r & 3) + 8 * (r >> 2) + 4 * hi;
    const size_t ro = (size_t)(row0 + rloc) * 256;
    out[ro + n0 + ln] = tanhf(a0[r] + bn0);
    out[ro + n0 + 32 + ln] = tanhf(a1[r] + bn1);
  }
}

extern "C" void kernel_launch(void* const* d_in, const int* in_sizes, int n_in,
                              void* d_out, int out_size, void* d_ws, size_t ws_size,
                              hipStream_t stream) {
  const float* e = (const float*)d_in[0];    // [8,4096,256]
  const float* d = (const float*)d_in[1];    // [8,1024,256]
  const float* W = (const float*)d_in[2];    // [512,256]
  const float* bias = (const float*)d_in[3]; // [256]
  float* out = (float*)d_out;

  char* p = (char*)d_ws;
  const size_t EB = (size_t)B_ * TE_ * H_ * 2;       // 16 MiB
  const size_t WB = (size_t)512 * 256 * 2;           // 256 KiB
  const size_t PB = (size_t)NS_ * NROW_ * H_ * 2;    // 32 MiB (bf16 partials)
  unsigned short* ehi = (unsigned short*)p;            p += EB;
  unsigned short* elo = (unsigned short*)p;            p += EB;
  unsigned short* eT  = (unsigned short*)p;            p += EB;
  unsigned short* WT  = (unsigned short*)p;            p += WB;
  unsigned short* pacc = (unsigned short*)p;           p += PB;
  float* pmv = (float*)p;                              p += (size_t)NS_ * NROW_ * 4;
  float* plv = (float*)p;                              // total ~84.6 MiB

  prep<<<dim3(2176), dim3(256), 0, stream>>>(e, W, ehi, elo, eT, WT);
  flash5<<<dim3(512), dim3(512), 0, stream>>>(ehi, elo, eT, d, pacc, pmv, plv);
  dense2<<<dim3(256), dim3(256), 0, stream>>>(pacc, pmv, plv, d, WT, bias, out);
}